// Round 4
// baseline (1109.201 us; speedup 1.0000x reference)
//
#include <hip/hip_runtime.h>
#include <hip/hip_bf16.h>

#define N_TOK 768
#define D_MODEL 512
#define CZd 128
#define NH 16
#define DHd 32

// ---------------------------------------------------------------------------
// Kernel 1: pair bias = LayerNorm(z) @ Wz^T, stored as bias[h][q][k]
// One 4-lane group per (q,k) pair; wave = 16 pairs. Interleaved 16B-chunk
// element partition keeps LDS Wz reads on 4 distinct banks.
// grid: (12, 768), block 256
// ---------------------------------------------------------------------------
__global__ __launch_bounds__(256) void bias_kernel(
    const float* __restrict__ z, const float* __restrict__ ln_w,
    const float* __restrict__ ln_b, const float* __restrict__ Wz,
    float* __restrict__ bias)
{
    __shared__ float sWz[NH * CZd];
    __shared__ float swb[2 * CZd];
    int t = threadIdx.x;
    for (int i = t; i < NH * CZd; i += 256) sWz[i] = Wz[i];
    if (t < CZd) { swb[t] = ln_w[t]; swb[CZd + t] = ln_b[t]; }
    __syncthreads();

    int q   = blockIdx.y;
    int k0  = blockIdx.x * 64;
    int lane = t & 63;
    int wv   = t >> 6;
    int g    = lane >> 2;   // group within wave (16 groups)
    int sub  = lane & 3;    // lane within group
    int k    = k0 + wv * 16 + g;

    const float* zrow = z + ((size_t)q * N_TOK + k) * CZd;

    float vals[32];
    float sum = 0.f, sumsq = 0.f;
#pragma unroll
    for (int i = 0; i < 8; ++i) {
        float4 v4 = *(const float4*)(zrow + (sub + 4 * i) * 4);
        vals[4*i+0] = v4.x; vals[4*i+1] = v4.y;
        vals[4*i+2] = v4.z; vals[4*i+3] = v4.w;
        sum   += v4.x + v4.y + v4.z + v4.w;
        sumsq += v4.x*v4.x + v4.y*v4.y + v4.z*v4.z + v4.w*v4.w;
    }
    sum   += __shfl_xor(sum, 1);   sum   += __shfl_xor(sum, 2);
    sumsq += __shfl_xor(sumsq, 1); sumsq += __shfl_xor(sumsq, 2);

    float mu   = sum * (1.f / CZd);
    float var  = sumsq * (1.f / CZd) - mu * mu;
    float rstd = rsqrtf(var + 1e-5f);

#pragma unroll
    for (int i = 0; i < 8; ++i) {
#pragma unroll
        for (int jj = 0; jj < 4; ++jj) {
            int e = 16 * i + 4 * sub + jj;
            vals[4*i+jj] = (vals[4*i+jj] - mu) * rstd * swb[e] + swb[CZd + e];
        }
    }

    float outv[NH];
#pragma unroll
    for (int h = 0; h < NH; ++h) {
        float p = 0.f;
#pragma unroll
        for (int i = 0; i < 8; ++i) {
#pragma unroll
            for (int jj = 0; jj < 4; ++jj) {
                int e = 16 * i + 4 * sub + jj;
                p += vals[4*i+jj] * sWz[h * CZd + e];
            }
        }
        p += __shfl_xor(p, 1); p += __shfl_xor(p, 2);
        outv[h] = p;
    }

#pragma unroll
    for (int j = 0; j < 4; ++j) {
        int h = j * 4 + sub;
        bias[((size_t)h * N_TOK + q) * N_TOK + k] = outv[h];
    }
}

// ---------------------------------------------------------------------------
// Kernel 2: fused projections  qkvg[n][j] (j<512:q +bq, <1024:k, <1536:v, else g)
// C = s @ W^T, tiled 64x64, BK=16, 256 threads, 4x4 per thread.
// grid: (32, 12), block 256
// ---------------------------------------------------------------------------
__global__ __launch_bounds__(256) void qkvg_kernel(
    const float* __restrict__ s,
    const float* __restrict__ Wq, const float* __restrict__ bq,
    const float* __restrict__ Wk, const float* __restrict__ Wv,
    const float* __restrict__ Wg, float* __restrict__ qkvg)
{
    __shared__ float As[16][65];
    __shared__ float Bs[16][65];
    int t  = threadIdx.x;
    int m0 = blockIdx.y * 64;
    int n0 = blockIdx.x * 64;
    int sel  = n0 >> 9;
    int nloc = n0 & 511;
    const float* W = (sel == 0) ? Wq : (sel == 1) ? Wk : (sel == 2) ? Wv : Wg;

    int tm = t >> 4, tn = t & 15;
    float acc[4][4] = {};

    for (int kt = 0; kt < 512; kt += 16) {
#pragma unroll
        for (int i = 0; i < 4; ++i) {
            int idx = t + i * 256;
            int r = idx >> 4, c = idx & 15;
            As[c][r] = s[(m0 + r) * 512 + kt + c];
            Bs[c][r] = W[(nloc + r) * 512 + kt + c];
        }
        __syncthreads();
#pragma unroll
        for (int kk = 0; kk < 16; ++kk) {
            float a[4], b[4];
#pragma unroll
            for (int i = 0; i < 4; ++i) a[i] = As[kk][tm * 4 + i];
#pragma unroll
            for (int j = 0; j < 4; ++j) b[j] = Bs[kk][tn * 4 + j];
#pragma unroll
            for (int i = 0; i < 4; ++i)
#pragma unroll
                for (int j = 0; j < 4; ++j)
                    acc[i][j] += a[i] * b[j];
        }
        __syncthreads();
    }

#pragma unroll
    for (int i = 0; i < 4; ++i) {
        int row = m0 + tm * 4 + i;
        float4 v;
        int colb = n0 + tn * 4;
        v.x = acc[i][0]; v.y = acc[i][1]; v.z = acc[i][2]; v.w = acc[i][3];
        if (sel == 0) {
            v.x += bq[colb + 0]; v.y += bq[colb + 1];
            v.z += bq[colb + 2]; v.w += bq[colb + 3];
        }
        *(float4*)&qkvg[(size_t)row * 2048 + colb] = v;
    }
}

// ---------------------------------------------------------------------------
// Kernel 3: attention for one head x 8 query rows.
// logits -> LDS, wave softmax, PV + sigmoid gate fused.
// grid: (96, 16), block 256
// ---------------------------------------------------------------------------
__global__ __launch_bounds__(256) void attn_kernel(
    const float* __restrict__ qkvg, const float* __restrict__ bias,
    float* __restrict__ o_g)
{
    __shared__ float l[8][768];
    __shared__ float qs[8][32];
    __shared__ float srsum[8];

    int t  = threadIdx.x;
    int h  = blockIdx.y;
    int Q0 = blockIdx.x * 8;

    {
        int qi = t >> 5, d = t & 31;
        qs[qi][d] = qkvg[(size_t)(Q0 + qi) * 2048 + h * 32 + d];
    }
    __syncthreads();

    const float scale = 0.17677669529663687f; // 1/sqrt(32)

    // phase 1: logits
#pragma unroll
    for (int j = 0; j < 3; ++j) {
        int kk = j * 256 + t;
        const float* krow = qkvg + (size_t)kk * 2048 + 512 + h * 32;
        float kv[32];
#pragma unroll
        for (int i = 0; i < 8; ++i) {
            float4 v4 = *(const float4*)(krow + i * 4);
            kv[4*i] = v4.x; kv[4*i+1] = v4.y; kv[4*i+2] = v4.z; kv[4*i+3] = v4.w;
        }
#pragma unroll
        for (int qi = 0; qi < 8; ++qi) {
            float dot = 0.f;
#pragma unroll
            for (int d = 0; d < 32; ++d) dot += kv[d] * qs[qi][d];
            l[qi][kk] = dot * scale +
                bias[((size_t)h * N_TOK + (Q0 + qi)) * N_TOK + kk];
        }
    }
    __syncthreads();

    // phase 2: softmax, wave wv handles rows 2wv, 2wv+1
    int lane = t & 63, wv = t >> 6;
    for (int r = 0; r < 2; ++r) {
        int row = wv * 2 + r;
        float m = -1e30f;
#pragma unroll
        for (int i = 0; i < 12; ++i) m = fmaxf(m, l[row][lane + i * 64]);
#pragma unroll
        for (int o = 32; o >= 1; o >>= 1) m = fmaxf(m, __shfl_xor(m, o));
        float ssum = 0.f;
#pragma unroll
        for (int i = 0; i < 12; ++i) {
            float p = expf(l[row][lane + i * 64] - m);
            l[row][lane + i * 64] = p;
            ssum += p;
        }
#pragma unroll
        for (int o = 32; o >= 1; o >>= 1) ssum += __shfl_xor(ssum, o);
        if (lane == 0) srsum[row] = 1.f / ssum;
    }
    __syncthreads();

    // phase 3: o = P @ v, then sigmoid gate
    {
        int qi = t >> 5, d = t & 31;
        float acc = 0.f;
        const float* vbase = qkvg + 1024 + h * 32 + d;
#pragma unroll 4
        for (int k = 0; k < 768; ++k) {
            acc += l[qi][k] * vbase[(size_t)k * 2048];
        }
        float gv = qkvg[(size_t)(Q0 + qi) * 2048 + 1536 + h * 32 + d];
        float og = acc * srsum[qi] / (1.f + expf(-gv));
        o_g[(size_t)(Q0 + qi) * 512 + h * 32 + d] = og;
    }
}

// ---------------------------------------------------------------------------
// Kernel 4: out = o_g @ Wo^T   (768x512 @ 512x512)
// grid: (8, 12), block 256
// ---------------------------------------------------------------------------
__global__ __launch_bounds__(256) void outproj_kernel(
    const float* __restrict__ o_g, const float* __restrict__ Wo,
    float* __restrict__ out)
{
    __shared__ float As[16][65];
    __shared__ float Bs[16][65];
    int t  = threadIdx.x;
    int m0 = blockIdx.y * 64;
    int n0 = blockIdx.x * 64;

    int tm = t >> 4, tn = t & 15;
    float acc[4][4] = {};

    for (int kt = 0; kt < 512; kt += 16) {
#pragma unroll
        for (int i = 0; i < 4; ++i) {
            int idx = t + i * 256;
            int r = idx >> 4, c = idx & 15;
            As[c][r] = o_g[(m0 + r) * 512 + kt + c];
            Bs[c][r] = Wo[(n0 + r) * 512 + kt + c];
        }
        __syncthreads();
#pragma unroll
        for (int kk = 0; kk < 16; ++kk) {
            float a[4], b[4];
#pragma unroll
            for (int i = 0; i < 4; ++i) a[i] = As[kk][tm * 4 + i];
#pragma unroll
            for (int j = 0; j < 4; ++j) b[j] = Bs[kk][tn * 4 + j];
#pragma unroll
            for (int i = 0; i < 4; ++i)
#pragma unroll
                for (int j = 0; j < 4; ++j)
                    acc[i][j] += a[i] * b[j];
        }
        __syncthreads();
    }

#pragma unroll
    for (int i = 0; i < 4; ++i) {
        int row = m0 + tm * 4 + i;
        float4 v;
        v.x = acc[i][0]; v.y = acc[i][1]; v.z = acc[i][2]; v.w = acc[i][3];
        *(float4*)&out[(size_t)row * 512 + n0 + tn * 4] = v;
    }
}

// ---------------------------------------------------------------------------
extern "C" void kernel_launch(void* const* d_in, const int* in_sizes, int n_in,
                              void* d_out, int out_size, void* d_ws, size_t ws_size,
                              hipStream_t stream)
{
    const float* s    = (const float*)d_in[0];
    const float* z    = (const float*)d_in[1];
    const float* Wq   = (const float*)d_in[2];
    const float* bq   = (const float*)d_in[3];
    const float* Wk   = (const float*)d_in[4];
    const float* Wv   = (const float*)d_in[5];
    const float* Wg   = (const float*)d_in[6];
    const float* Wo   = (const float*)d_in[7];
    const float* ln_w = (const float*)d_in[8];
    const float* ln_b = (const float*)d_in[9];
    const float* Wz   = (const float*)d_in[10];

    float* ws    = (float*)d_ws;
    float* qkvg  = ws;                                   // 768*2048 floats
    float* biasb = qkvg + (size_t)N_TOK * 2048;          // 16*768*768 floats
    float* o_g   = biasb + (size_t)NH * N_TOK * N_TOK;   // 768*512 floats
    float* out   = (float*)d_out;

    hipLaunchKernelGGL(qkvg_kernel, dim3(32, 12), dim3(256), 0, stream,
                       s, Wq, bq, Wk, Wv, Wg, qkvg);
    hipLaunchKernelGGL(bias_kernel, dim3(12, 768), dim3(256), 0, stream,
                       z, ln_w, ln_b, Wz, biasb);
    hipLaunchKernelGGL(attn_kernel, dim3(96, 16), dim3(256), 0, stream,
                       qkvg, biasb, o_g);
    hipLaunchKernelGGL(outproj_kernel, dim3(8, 12), dim3(256), 0, stream,
                       o_g, Wo, out);
}

// Round 5
// 600.754 us; speedup vs baseline: 1.8463x; 1.8463x over previous
//
#include <hip/hip_runtime.h>
#include <hip/hip_bf16.h>

#define N_TOK 768
#define D_MODEL 512
#define CZd 128
#define NH 16
#define DHd 32

// ---------------------------------------------------------------------------
// Kernel 1: pair bias = LayerNorm(z) @ Wz^T, stored as bias[h][q][k]
// (unchanged from round 4 baseline)
// grid: (12, 768), block 256
// ---------------------------------------------------------------------------
__global__ __launch_bounds__(256) void bias_kernel(
    const float* __restrict__ z, const float* __restrict__ ln_w,
    const float* __restrict__ ln_b, const float* __restrict__ Wz,
    float* __restrict__ bias)
{
    __shared__ float sWz[NH * CZd];
    __shared__ float swb[2 * CZd];
    int t = threadIdx.x;
    for (int i = t; i < NH * CZd; i += 256) sWz[i] = Wz[i];
    if (t < CZd) { swb[t] = ln_w[t]; swb[CZd + t] = ln_b[t]; }
    __syncthreads();

    int q   = blockIdx.y;
    int k0  = blockIdx.x * 64;
    int lane = t & 63;
    int wv   = t >> 6;
    int g    = lane >> 2;   // group within wave (16 groups)
    int sub  = lane & 3;    // lane within group
    int k    = k0 + wv * 16 + g;

    const float* zrow = z + ((size_t)q * N_TOK + k) * CZd;

    float vals[32];
    float sum = 0.f, sumsq = 0.f;
#pragma unroll
    for (int i = 0; i < 8; ++i) {
        float4 v4 = *(const float4*)(zrow + (sub + 4 * i) * 4);
        vals[4*i+0] = v4.x; vals[4*i+1] = v4.y;
        vals[4*i+2] = v4.z; vals[4*i+3] = v4.w;
        sum   += v4.x + v4.y + v4.z + v4.w;
        sumsq += v4.x*v4.x + v4.y*v4.y + v4.z*v4.z + v4.w*v4.w;
    }
    sum   += __shfl_xor(sum, 1);   sum   += __shfl_xor(sum, 2);
    sumsq += __shfl_xor(sumsq, 1); sumsq += __shfl_xor(sumsq, 2);

    float mu   = sum * (1.f / CZd);
    float var  = sumsq * (1.f / CZd) - mu * mu;
    float rstd = rsqrtf(var + 1e-5f);

#pragma unroll
    for (int i = 0; i < 8; ++i) {
#pragma unroll
        for (int jj = 0; jj < 4; ++jj) {
            int e = 16 * i + 4 * sub + jj;
            vals[4*i+jj] = (vals[4*i+jj] - mu) * rstd * swb[e] + swb[CZd + e];
        }
    }

    float outv[NH];
#pragma unroll
    for (int h = 0; h < NH; ++h) {
        float p = 0.f;
#pragma unroll
        for (int i = 0; i < 8; ++i) {
#pragma unroll
            for (int jj = 0; jj < 4; ++jj) {
                int e = 16 * i + 4 * sub + jj;
                p += vals[4*i+jj] * sWz[h * CZd + e];
            }
        }
        p += __shfl_xor(p, 1); p += __shfl_xor(p, 2);
        outv[h] = p;
    }

#pragma unroll
    for (int j = 0; j < 4; ++j) {
        int h = j * 4 + sub;
        bias[((size_t)h * N_TOK + q) * N_TOK + k] = outv[h];
    }
}

// ---------------------------------------------------------------------------
// Kernel 2: fused projections (unchanged)
// grid: (32, 12), block 256
// ---------------------------------------------------------------------------
__global__ __launch_bounds__(256) void qkvg_kernel(
    const float* __restrict__ s,
    const float* __restrict__ Wq, const float* __restrict__ bq,
    const float* __restrict__ Wk, const float* __restrict__ Wv,
    const float* __restrict__ Wg, float* __restrict__ qkvg)
{
    __shared__ float As[16][65];
    __shared__ float Bs[16][65];
    int t  = threadIdx.x;
    int m0 = blockIdx.y * 64;
    int n0 = blockIdx.x * 64;
    int sel  = n0 >> 9;
    int nloc = n0 & 511;
    const float* W = (sel == 0) ? Wq : (sel == 1) ? Wk : (sel == 2) ? Wv : Wg;

    int tm = t >> 4, tn = t & 15;
    float acc[4][4] = {};

    for (int kt = 0; kt < 512; kt += 16) {
#pragma unroll
        for (int i = 0; i < 4; ++i) {
            int idx = t + i * 256;
            int r = idx >> 4, c = idx & 15;
            As[c][r] = s[(m0 + r) * 512 + kt + c];
            Bs[c][r] = W[(nloc + r) * 512 + kt + c];
        }
        __syncthreads();
#pragma unroll
        for (int kk = 0; kk < 16; ++kk) {
            float a[4], b[4];
#pragma unroll
            for (int i = 0; i < 4; ++i) a[i] = As[kk][tm * 4 + i];
#pragma unroll
            for (int j = 0; j < 4; ++j) b[j] = Bs[kk][tn * 4 + j];
#pragma unroll
            for (int i = 0; i < 4; ++i)
#pragma unroll
                for (int j = 0; j < 4; ++j)
                    acc[i][j] += a[i] * b[j];
        }
        __syncthreads();
    }

#pragma unroll
    for (int i = 0; i < 4; ++i) {
        int row = m0 + tm * 4 + i;
        float4 v;
        int colb = n0 + tn * 4;
        v.x = acc[i][0]; v.y = acc[i][1]; v.z = acc[i][2]; v.w = acc[i][3];
        if (sel == 0) {
            v.x += bq[colb + 0]; v.y += bq[colb + 1];
            v.z += bq[colb + 2]; v.w += bq[colb + 3];
        }
        *(float4*)&qkvg[(size_t)row * 2048 + colb] = v;
    }
}

// ---------------------------------------------------------------------------
// Kernel 3 (REWRITTEN): flash-style tiled attention.
// Block = (head h, 16 q-rows). Loop over 12 k-tiles of 64:
//   stage K/V tile to LDS (coalesced 128B lines; K tile XOR-swizzled),
//   logits from LDS (q-row in regs), online softmax (running m,l),
//   PV accumulate in regs (vt reads lane-consecutive, conflict-free).
// LDS ~20.4 KB. grid: (48, 16), block 256.
// ---------------------------------------------------------------------------
#define QT 16
#define KT 64

__global__ __launch_bounds__(256) void attn_kernel(
    const float* __restrict__ qkvg, const float* __restrict__ bias,
    float* __restrict__ o_g)
{
    __shared__ float kt_s[KT][32];   // chunk c4 stored at (c4 ^ (row&7))
    __shared__ float vt_s[KT][32];   // row-major plain
    __shared__ __align__(16) float pt[QT][68];   // padded, 16B-aligned rows
    __shared__ float mrun[QT], lrun[QT], scalef[QT];

    int t  = threadIdx.x;
    int h  = blockIdx.y;
    int Q0 = blockIdx.x * QT;

    // logits ownership: row qi_l = t>>4, kk = (t&15) + 16j
    int qi_l = t >> 4;
    int c16  = t & 15;
    // PV ownership: d = t&31, rows qg*2, qg*2+1
    int d   = t & 31;
    int qg  = t >> 5;
    int qi0 = qg * 2, qi1 = qg * 2 + 1;

    // q-row of this thread's logit row -> registers (one-time, L2)
    float4 qreg[8];
    {
        const float* qrow = qkvg + (size_t)(Q0 + qi_l) * 2048 + h * 32;
#pragma unroll
        for (int j = 0; j < 8; ++j) qreg[j] = ((const float4*)qrow)[j];
    }

    float acc0 = 0.f, acc1 = 0.f;
    if (t < QT) { mrun[t] = -1e30f; lrun[t] = 0.f; }
    __syncthreads();

    const float scale = 0.17677669529663687f; // 1/sqrt(32)

    for (int k0 = 0; k0 < N_TOK; k0 += KT) {
        // ---- stage K/V tile (coalesced: 8 threads = one 128B row line) ----
#pragma unroll
        for (int i = 0; i < 2; ++i) {
            int idx = t + i * 256;          // 0..511
            int row = idx >> 3;             // 0..63
            int c4  = idx & 7;              // 0..7
            const float* kp = qkvg + (size_t)(k0 + row) * 2048 +  512 + h * 32 + c4 * 4;
            const float* vp = qkvg + (size_t)(k0 + row) * 2048 + 1024 + h * 32 + c4 * 4;
            float4 k4 = *(const float4*)kp;
            float4 v4 = *(const float4*)vp;
            int sc4 = c4 ^ (row & 7);
            *(float4*)&kt_s[row][sc4 * 4] = k4;
            *(float4*)&vt_s[row][c4 * 4]  = v4;
        }
        __syncthreads();

        // ---- logits: 4 dots per thread ----
#pragma unroll
        for (int j = 0; j < 4; ++j) {
            int kk = c16 + 16 * j;
            float dot = 0.f;
#pragma unroll
            for (int c4 = 0; c4 < 8; ++c4) {
                int sc4 = c4 ^ (kk & 7);
                float4 k4 = *(const float4*)&kt_s[kk][sc4 * 4];
                float4 q4 = qreg[c4];
                dot += k4.x*q4.x + k4.y*q4.y + k4.z*q4.z + k4.w*q4.w;
            }
            float b = bias[((size_t)h * N_TOK + (Q0 + qi_l)) * N_TOK + k0 + kk];
            pt[qi_l][kk] = dot * scale + b;
        }
        __syncthreads();

        // ---- online softmax: wave w owns rows 4w..4w+3 ----
        {
            int lane = t & 63, w = t >> 6;
#pragma unroll
            for (int r4 = 0; r4 < 4; ++r4) {
                int r = w * 4 + r4;
                float x = pt[r][lane];
                float mx = x;
#pragma unroll
                for (int o = 32; o >= 1; o >>= 1) mx = fmaxf(mx, __shfl_xor(mx, o));
                float mold = mrun[r];
                float mnew = fmaxf(mold, mx);
                float p = __expf(x - mnew);
                float ssum = p;
#pragma unroll
                for (int o = 32; o >= 1; o >>= 1) ssum += __shfl_xor(ssum, o);
                pt[r][lane] = p;
                if (lane == 0) {
                    float sc = __expf(mold - mnew);
                    scalef[r] = sc;
                    mrun[r]   = mnew;
                    lrun[r]   = lrun[r] * sc + ssum;
                }
            }
        }
        __syncthreads();

        // ---- PV accumulate ----
        {
            float s0 = scalef[qi0], s1 = scalef[qi1];
            acc0 *= s0; acc1 *= s1;
#pragma unroll
            for (int kk4 = 0; kk4 < KT; kk4 += 4) {
                float4 p0 = *(const float4*)&pt[qi0][kk4];
                float4 p1 = *(const float4*)&pt[qi1][kk4];
                float v0 = vt_s[kk4+0][d];
                float v1 = vt_s[kk4+1][d];
                float v2 = vt_s[kk4+2][d];
                float v3 = vt_s[kk4+3][d];
                acc0 += p0.x*v0 + p0.y*v1 + p0.z*v2 + p0.w*v3;
                acc1 += p1.x*v0 + p1.y*v1 + p1.z*v2 + p1.w*v3;
            }
        }
        __syncthreads();   // protect kt/vt/pt before next stage
    }

    // ---- epilogue: normalize, sigmoid gate, store ----
    {
        float g0 = qkvg[(size_t)(Q0 + qi0) * 2048 + 1536 + h * 32 + d];
        float g1 = qkvg[(size_t)(Q0 + qi1) * 2048 + 1536 + h * 32 + d];
        float o0 = acc0 / lrun[qi0] / (1.f + __expf(-g0));
        float o1 = acc1 / lrun[qi1] / (1.f + __expf(-g1));
        o_g[(size_t)(Q0 + qi0) * 512 + h * 32 + d] = o0;
        o_g[(size_t)(Q0 + qi1) * 512 + h * 32 + d] = o1;
    }
}

// ---------------------------------------------------------------------------
// Kernel 4: out = o_g @ Wo^T (unchanged)
// grid: (8, 12), block 256
// ---------------------------------------------------------------------------
__global__ __launch_bounds__(256) void outproj_kernel(
    const float* __restrict__ o_g, const float* __restrict__ Wo,
    float* __restrict__ out)
{
    __shared__ float As[16][65];
    __shared__ float Bs[16][65];
    int t  = threadIdx.x;
    int m0 = blockIdx.y * 64;
    int n0 = blockIdx.x * 64;

    int tm = t >> 4, tn = t & 15;
    float acc[4][4] = {};

    for (int kt = 0; kt < 512; kt += 16) {
#pragma unroll
        for (int i = 0; i < 4; ++i) {
            int idx = t + i * 256;
            int r = idx >> 4, c = idx & 15;
            As[c][r] = o_g[(m0 + r) * 512 + kt + c];
            Bs[c][r] = Wo[(n0 + r) * 512 + kt + c];
        }
        __syncthreads();
#pragma unroll
        for (int kk = 0; kk < 16; ++kk) {
            float a[4], b[4];
#pragma unroll
            for (int i = 0; i < 4; ++i) a[i] = As[kk][tm * 4 + i];
#pragma unroll
            for (int j = 0; j < 4; ++j) b[j] = Bs[kk][tn * 4 + j];
#pragma unroll
            for (int i = 0; i < 4; ++i)
#pragma unroll
                for (int j = 0; j < 4; ++j)
                    acc[i][j] += a[i] * b[j];
        }
        __syncthreads();
    }

#pragma unroll
    for (int i = 0; i < 4; ++i) {
        int row = m0 + tm * 4 + i;
        float4 v;
        v.x = acc[i][0]; v.y = acc[i][1]; v.z = acc[i][2]; v.w = acc[i][3];
        *(float4*)&out[(size_t)row * 512 + n0 + tn * 4] = v;
    }
}

// ---------------------------------------------------------------------------
extern "C" void kernel_launch(void* const* d_in, const int* in_sizes, int n_in,
                              void* d_out, int out_size, void* d_ws, size_t ws_size,
                              hipStream_t stream)
{
    const float* s    = (const float*)d_in[0];
    const float* z    = (const float*)d_in[1];
    const float* Wq   = (const float*)d_in[2];
    const float* bq   = (const float*)d_in[3];
    const float* Wk   = (const float*)d_in[4];
    const float* Wv   = (const float*)d_in[5];
    const float* Wg   = (const float*)d_in[6];
    const float* Wo   = (const float*)d_in[7];
    const float* ln_w = (const float*)d_in[8];
    const float* ln_b = (const float*)d_in[9];
    const float* Wz   = (const float*)d_in[10];

    float* ws    = (float*)d_ws;
    float* qkvg  = ws;                                   // 768*2048 floats
    float* biasb = qkvg + (size_t)N_TOK * 2048;          // 16*768*768 floats
    float* o_g   = biasb + (size_t)NH * N_TOK * N_TOK;   // 768*512 floats
    float* out   = (float*)d_out;

    hipLaunchKernelGGL(qkvg_kernel, dim3(32, 12), dim3(256), 0, stream,
                       s, Wq, bq, Wk, Wv, Wg, qkvg);
    hipLaunchKernelGGL(bias_kernel, dim3(12, 768), dim3(256), 0, stream,
                       z, ln_w, ln_b, Wz, biasb);
    hipLaunchKernelGGL(attn_kernel, dim3(48, 16), dim3(256), 0, stream,
                       qkvg, biasb, o_g);
    hipLaunchKernelGGL(outproj_kernel, dim3(8, 12), dim3(256), 0, stream,
                       o_g, Wo, out);
}

// Round 8
// 575.106 us; speedup vs baseline: 1.9287x; 1.0446x over previous
//
#include <hip/hip_runtime.h>
#include <hip/hip_bf16.h>

#define N_TOK 768
#define D_MODEL 512
#define CZd 128
#define NH 16
#define DHd 32

// ---------------------------------------------------------------------------
// Kernel 1: pair bias = LayerNorm(z) @ Wz^T, stored as bias[h][q][k]
// Compute unchanged; store path now goes through LDS transpose so each
// wave writes 256B-contiguous float4 runs per h-plane.
// grid: (12, 768), block 256
// ---------------------------------------------------------------------------
__global__ __launch_bounds__(256) void bias_kernel(
    const float* __restrict__ z, const float* __restrict__ ln_w,
    const float* __restrict__ ln_b, const float* __restrict__ Wz,
    float* __restrict__ bias)
{
    __shared__ float sWz[NH * CZd];
    __shared__ float swb[2 * CZd];
    __shared__ __align__(16) float sbias[NH][68];   // 272B rows: 16B-aligned
    int t = threadIdx.x;
    for (int i = t; i < NH * CZd; i += 256) sWz[i] = Wz[i];
    if (t < CZd) { swb[t] = ln_w[t]; swb[CZd + t] = ln_b[t]; }
    __syncthreads();

    int q   = blockIdx.y;
    int k0  = blockIdx.x * 64;
    int lane = t & 63;
    int wv   = t >> 6;
    int g    = lane >> 2;   // group within wave (16 groups)
    int sub  = lane & 3;    // lane within group
    int k    = k0 + wv * 16 + g;

    const float* zrow = z + ((size_t)q * N_TOK + k) * CZd;

    float vals[32];
    float sum = 0.f, sumsq = 0.f;
#pragma unroll
    for (int i = 0; i < 8; ++i) {
        float4 v4 = *(const float4*)(zrow + (sub + 4 * i) * 4);
        vals[4*i+0] = v4.x; vals[4*i+1] = v4.y;
        vals[4*i+2] = v4.z; vals[4*i+3] = v4.w;
        sum   += v4.x + v4.y + v4.z + v4.w;
        sumsq += v4.x*v4.x + v4.y*v4.y + v4.z*v4.z + v4.w*v4.w;
    }
    sum   += __shfl_xor(sum, 1);   sum   += __shfl_xor(sum, 2);
    sumsq += __shfl_xor(sumsq, 1); sumsq += __shfl_xor(sumsq, 2);

    float mu   = sum * (1.f / CZd);
    float var  = sumsq * (1.f / CZd) - mu * mu;
    float rstd = rsqrtf(var + 1e-5f);

#pragma unroll
    for (int i = 0; i < 8; ++i) {
#pragma unroll
        for (int jj = 0; jj < 4; ++jj) {
            int e = 16 * i + 4 * sub + jj;
            vals[4*i+jj] = (vals[4*i+jj] - mu) * rstd * swb[e] + swb[CZd + e];
        }
    }

#pragma unroll
    for (int h = 0; h < NH; ++h) {
        float p = 0.f;
#pragma unroll
        for (int i = 0; i < 8; ++i) {
#pragma unroll
            for (int jj = 0; jj < 4; ++jj) {
                int e = 16 * i + 4 * sub + jj;
                p += vals[4*i+jj] * sWz[h * CZd + e];
            }
        }
        p += __shfl_xor(p, 1); p += __shfl_xor(p, 2);
        if ((h & 3) == sub) sbias[h][wv * 16 + g] = p;
    }
    __syncthreads();

    // coalesced store: thread t -> h = t>>4, 4 consecutive k
    {
        int h  = t >> 4;
        int c4 = t & 15;
        float4 v = *(const float4*)&sbias[h][c4 * 4];
        *(float4*)&bias[((size_t)h * N_TOK + q) * N_TOK + k0 + c4 * 4] = v;
    }
}

// ---------------------------------------------------------------------------
// Kernel 2 (REWORKED): fused projections, C = s @ W^T
// k-major LDS tiles [BK=32][68] (16B-aligned rows -> ds_read_b128,
// 2-way-free banks), 128B-line coalesced global loads, 64x64 tile,
// 4x4 per thread. Same sequential k accumulation order as before.
// grid: (32, 12), block 256
// ---------------------------------------------------------------------------
#define BKP 32

__global__ __launch_bounds__(256) void qkvg_kernel(
    const float* __restrict__ s,
    const float* __restrict__ Wq, const float* __restrict__ bq,
    const float* __restrict__ Wk, const float* __restrict__ Wv,
    const float* __restrict__ Wg, float* __restrict__ qkvg)
{
    __shared__ __align__(16) float As[BKP][68];   // [k][m]
    __shared__ __align__(16) float Bs[BKP][68];   // [k][n]
    int t  = threadIdx.x;
    int m0 = blockIdx.y * 64;
    int n0 = blockIdx.x * 64;
    int sel  = n0 >> 9;
    int nloc = n0 & 511;
    const float* W = (sel == 0) ? Wq : (sel == 1) ? Wk : (sel == 2) ? Wv : Wg;

    int tm = t >> 4, tn = t & 15;
    float acc[4][4] = {};

    for (int kt = 0; kt < 512; kt += BKP) {
#pragma unroll
        for (int i = 0; i < 2; ++i) {
            int idx = t + i * 256;          // 0..511
            int row = idx >> 3;             // 0..63
            int c4  = idx & 7;              // 0..7 -> k-chunk
            float4 a4 = *(const float4*)&s[(size_t)(m0 + row) * 512 + kt + c4 * 4];
            float4 b4 = *(const float4*)&W[(size_t)(nloc + row) * 512 + kt + c4 * 4];
            As[c4*4+0][row] = a4.x; As[c4*4+1][row] = a4.y;
            As[c4*4+2][row] = a4.z; As[c4*4+3][row] = a4.w;
            Bs[c4*4+0][row] = b4.x; Bs[c4*4+1][row] = b4.y;
            Bs[c4*4+2][row] = b4.z; Bs[c4*4+3][row] = b4.w;
        }
        __syncthreads();
#pragma unroll
        for (int kk = 0; kk < BKP; ++kk) {
            float4 a4 = *(const float4*)&As[kk][tm * 4];
            float4 b4 = *(const float4*)&Bs[kk][tn * 4];
            acc[0][0] += a4.x * b4.x; acc[0][1] += a4.x * b4.y;
            acc[0][2] += a4.x * b4.z; acc[0][3] += a4.x * b4.w;
            acc[1][0] += a4.y * b4.x; acc[1][1] += a4.y * b4.y;
            acc[1][2] += a4.y * b4.z; acc[1][3] += a4.y * b4.w;
            acc[2][0] += a4.z * b4.x; acc[2][1] += a4.z * b4.y;
            acc[2][2] += a4.z * b4.z; acc[2][3] += a4.z * b4.w;
            acc[3][0] += a4.w * b4.x; acc[3][1] += a4.w * b4.y;
            acc[3][2] += a4.w * b4.z; acc[3][3] += a4.w * b4.w;
        }
        __syncthreads();
    }

#pragma unroll
    for (int i = 0; i < 4; ++i) {
        int row = m0 + tm * 4 + i;
        float4 v;
        int colb = n0 + tn * 4;
        v.x = acc[i][0]; v.y = acc[i][1]; v.z = acc[i][2]; v.w = acc[i][3];
        if (sel == 0) {
            v.x += bq[colb + 0]; v.y += bq[colb + 1];
            v.z += bq[colb + 2]; v.w += bq[colb + 3];
        }
        *(float4*)&qkvg[(size_t)row * 2048 + colb] = v;
    }
}

// ---------------------------------------------------------------------------
// Kernel 3: flash-style tiled attention (unchanged from round 5)
// grid: (48, 16), block 256
// ---------------------------------------------------------------------------
#define QT 16
#define KT 64

__global__ __launch_bounds__(256) void attn_kernel(
    const float* __restrict__ qkvg, const float* __restrict__ bias,
    float* __restrict__ o_g)
{
    __shared__ float kt_s[KT][32];   // chunk c4 stored at (c4 ^ (row&7))
    __shared__ float vt_s[KT][32];   // row-major plain
    __shared__ __align__(16) float pt[QT][68];
    __shared__ float mrun[QT], lrun[QT], scalef[QT];

    int t  = threadIdx.x;
    int h  = blockIdx.y;
    int Q0 = blockIdx.x * QT;

    int qi_l = t >> 4;
    int c16  = t & 15;
    int d   = t & 31;
    int qg  = t >> 5;
    int qi0 = qg * 2, qi1 = qg * 2 + 1;

    float4 qreg[8];
    {
        const float* qrow = qkvg + (size_t)(Q0 + qi_l) * 2048 + h * 32;
#pragma unroll
        for (int j = 0; j < 8; ++j) qreg[j] = ((const float4*)qrow)[j];
    }

    float acc0 = 0.f, acc1 = 0.f;
    if (t < QT) { mrun[t] = -1e30f; lrun[t] = 0.f; }
    __syncthreads();

    const float scale = 0.17677669529663687f; // 1/sqrt(32)

    for (int k0 = 0; k0 < N_TOK; k0 += KT) {
#pragma unroll
        for (int i = 0; i < 2; ++i) {
            int idx = t + i * 256;
            int row = idx >> 3;
            int c4  = idx & 7;
            const float* kp = qkvg + (size_t)(k0 + row) * 2048 +  512 + h * 32 + c4 * 4;
            const float* vp = qkvg + (size_t)(k0 + row) * 2048 + 1024 + h * 32 + c4 * 4;
            float4 k4 = *(const float4*)kp;
            float4 v4 = *(const float4*)vp;
            int sc4 = c4 ^ (row & 7);
            *(float4*)&kt_s[row][sc4 * 4] = k4;
            *(float4*)&vt_s[row][c4 * 4]  = v4;
        }
        __syncthreads();

#pragma unroll
        for (int j = 0; j < 4; ++j) {
            int kk = c16 + 16 * j;
            float dot = 0.f;
#pragma unroll
            for (int c4 = 0; c4 < 8; ++c4) {
                int sc4 = c4 ^ (kk & 7);
                float4 k4 = *(const float4*)&kt_s[kk][sc4 * 4];
                float4 q4 = qreg[c4];
                dot += k4.x*q4.x + k4.y*q4.y + k4.z*q4.z + k4.w*q4.w;
            }
            float b = bias[((size_t)h * N_TOK + (Q0 + qi_l)) * N_TOK + k0 + kk];
            pt[qi_l][kk] = dot * scale + b;
        }
        __syncthreads();

        {
            int lane = t & 63, w = t >> 6;
#pragma unroll
            for (int r4 = 0; r4 < 4; ++r4) {
                int r = w * 4 + r4;
                float x = pt[r][lane];
                float mx = x;
#pragma unroll
                for (int o = 32; o >= 1; o >>= 1) mx = fmaxf(mx, __shfl_xor(mx, o));
                float mold = mrun[r];
                float mnew = fmaxf(mold, mx);
                float p = __expf(x - mnew);
                float ssum = p;
#pragma unroll
                for (int o = 32; o >= 1; o >>= 1) ssum += __shfl_xor(ssum, o);
                pt[r][lane] = p;
                if (lane == 0) {
                    float sc = __expf(mold - mnew);
                    scalef[r] = sc;
                    mrun[r]   = mnew;
                    lrun[r]   = lrun[r] * sc + ssum;
                }
            }
        }
        __syncthreads();

        {
            float s0 = scalef[qi0], s1 = scalef[qi1];
            acc0 *= s0; acc1 *= s1;
#pragma unroll
            for (int kk4 = 0; kk4 < KT; kk4 += 4) {
                float4 p0 = *(const float4*)&pt[qi0][kk4];
                float4 p1 = *(const float4*)&pt[qi1][kk4];
                float v0 = vt_s[kk4+0][d];
                float v1 = vt_s[kk4+1][d];
                float v2 = vt_s[kk4+2][d];
                float v3 = vt_s[kk4+3][d];
                acc0 += p0.x*v0 + p0.y*v1 + p0.z*v2 + p0.w*v3;
                acc1 += p1.x*v0 + p1.y*v1 + p1.z*v2 + p1.w*v3;
            }
        }
        __syncthreads();
    }

    {
        float g0 = qkvg[(size_t)(Q0 + qi0) * 2048 + 1536 + h * 32 + d];
        float g1 = qkvg[(size_t)(Q0 + qi1) * 2048 + 1536 + h * 32 + d];
        float o0 = acc0 / lrun[qi0] / (1.f + __expf(-g0));
        float o1 = acc1 / lrun[qi1] / (1.f + __expf(-g1));
        o_g[(size_t)(Q0 + qi0) * 512 + h * 32 + d] = o0;
        o_g[(size_t)(Q0 + qi1) * 512 + h * 32 + d] = o1;
    }
}

// ---------------------------------------------------------------------------
// Kernel 4 (REWORKED, same structure as qkvg): out = o_g @ Wo^T
// grid: (8, 12), block 256
// ---------------------------------------------------------------------------
__global__ __launch_bounds__(256) void outproj_kernel(
    const float* __restrict__ o_g, const float* __restrict__ Wo,
    float* __restrict__ out)
{
    __shared__ __align__(16) float As[BKP][68];
    __shared__ __align__(16) float Bs[BKP][68];
    int t  = threadIdx.x;
    int m0 = blockIdx.y * 64;
    int n0 = blockIdx.x * 64;

    int tm = t >> 4, tn = t & 15;
    float acc[4][4] = {};

    for (int kt = 0; kt < 512; kt += BKP) {
#pragma unroll
        for (int i = 0; i < 2; ++i) {
            int idx = t + i * 256;
            int row = idx >> 3;
            int c4  = idx & 7;
            float4 a4 = *(const float4*)&o_g[(size_t)(m0 + row) * 512 + kt + c4 * 4];
            float4 b4 = *(const float4*)&Wo[(size_t)(n0 + row) * 512 + kt + c4 * 4];
            As[c4*4+0][row] = a4.x; As[c4*4+1][row] = a4.y;
            As[c4*4+2][row] = a4.z; As[c4*4+3][row] = a4.w;
            Bs[c4*4+0][row] = b4.x; Bs[c4*4+1][row] = b4.y;
            Bs[c4*4+2][row] = b4.z; Bs[c4*4+3][row] = b4.w;
        }
        __syncthreads();
#pragma unroll
        for (int kk = 0; kk < BKP; ++kk) {
            float4 a4 = *(const float4*)&As[kk][tm * 4];
            float4 b4 = *(const float4*)&Bs[kk][tn * 4];
            acc[0][0] += a4.x * b4.x; acc[0][1] += a4.x * b4.y;
            acc[0][2] += a4.x * b4.z; acc[0][3] += a4.x * b4.w;
            acc[1][0] += a4.y * b4.x; acc[1][1] += a4.y * b4.y;
            acc[1][2] += a4.y * b4.z; acc[1][3] += a4.y * b4.w;
            acc[2][0] += a4.z * b4.x; acc[2][1] += a4.z * b4.y;
            acc[2][2] += a4.z * b4.z; acc[2][3] += a4.z * b4.w;
            acc[3][0] += a4.w * b4.x; acc[3][1] += a4.w * b4.y;
            acc[3][2] += a4.w * b4.z; acc[3][3] += a4.w * b4.w;
        }
        __syncthreads();
    }

#pragma unroll
    for (int i = 0; i < 4; ++i) {
        int row = m0 + tm * 4 + i;
        float4 v;
        v.x = acc[i][0]; v.y = acc[i][1]; v.z = acc[i][2]; v.w = acc[i][3];
        *(float4*)&out[(size_t)row * 512 + n0 + tn * 4] = v;
    }
}

// ---------------------------------------------------------------------------
extern "C" void kernel_launch(void* const* d_in, const int* in_sizes, int n_in,
                              void* d_out, int out_size, void* d_ws, size_t ws_size,
                              hipStream_t stream)
{
    const float* s    = (const float*)d_in[0];
    const float* z    = (const float*)d_in[1];
    const float* Wq   = (const float*)d_in[2];
    const float* bq   = (const float*)d_in[3];
    const float* Wk   = (const float*)d_in[4];
    const float* Wv   = (const float*)d_in[5];
    const float* Wg   = (const float*)d_in[6];
    const float* Wo   = (const float*)d_in[7];
    const float* ln_w = (const float*)d_in[8];
    const float* ln_b = (const float*)d_in[9];
    const float* Wz   = (const float*)d_in[10];

    float* ws    = (float*)d_ws;
    float* qkvg  = ws;                                   // 768*2048 floats
    float* biasb = qkvg + (size_t)N_TOK * 2048;          // 16*768*768 floats
    float* o_g   = biasb + (size_t)NH * N_TOK * N_TOK;   // 768*512 floats
    float* out   = (float*)d_out;

    hipLaunchKernelGGL(qkvg_kernel, dim3(32, 12), dim3(256), 0, stream,
                       s, Wq, bq, Wk, Wv, Wg, qkvg);
    hipLaunchKernelGGL(bias_kernel, dim3(12, 768), dim3(256), 0, stream,
                       z, ln_w, ln_b, Wz, biasb);
    hipLaunchKernelGGL(attn_kernel, dim3(48, 16), dim3(256), 0, stream,
                       qkvg, biasb, o_g);
    hipLaunchKernelGGL(outproj_kernel, dim3(8, 12), dim3(256), 0, stream,
                       o_g, Wo, out);
}

// Round 10
// 552.431 us; speedup vs baseline: 2.0079x; 1.0410x over previous
//
#include <hip/hip_runtime.h>
#include <hip/hip_bf16.h>

#define N_TOK 768
#define D_MODEL 512
#define CZd 128
#define NH 16
#define DHd 32

// ---------------------------------------------------------------------------
// Kernel 1: pair bias = LayerNorm(z) @ Wz^T, stored as bias[h][q][k]
// v3: TWO q-rows per block -> each Wz ds_read_b128 feeds 2 pairs' FMAs,
// halving LDS traffic (4.8 GB -> 2.4 GB); z HBM stream (302 MB) is the floor.
// grid: (12, 384), block 256
// ---------------------------------------------------------------------------
__global__ __launch_bounds__(256) void bias_kernel(
    const float* __restrict__ z, const float* __restrict__ ln_w,
    const float* __restrict__ ln_b, const float* __restrict__ Wz,
    float* __restrict__ bias)
{
    __shared__ float sWz[NH * CZd];
    __shared__ float swb[2 * CZd];
    __shared__ __align__(16) float sbias[2][NH][68];   // 272B rows: 16B-aligned
    int t = threadIdx.x;
    for (int i = t; i < NH * CZd; i += 256) sWz[i] = Wz[i];
    if (t < CZd) { swb[t] = ln_w[t]; swb[CZd + t] = ln_b[t]; }
    __syncthreads();

    int q0  = blockIdx.y * 2;
    int k0  = blockIdx.x * 64;
    int lane = t & 63;
    int wv   = t >> 6;
    int g    = lane >> 2;   // group within wave (16 groups)
    int sub  = lane & 3;    // lane within group
    int k    = k0 + wv * 16 + g;

    const float* zrow0 = z + ((size_t)q0 * N_TOK + k) * CZd;
    const float* zrow1 = zrow0 + (size_t)N_TOK * CZd;

    float vals0[32], vals1[32];
    float sum0 = 0.f, sq0 = 0.f, sum1 = 0.f, sq1 = 0.f;
#pragma unroll
    for (int i = 0; i < 8; ++i) {
        float4 a = *(const float4*)(zrow0 + (sub + 4 * i) * 4);
        float4 b = *(const float4*)(zrow1 + (sub + 4 * i) * 4);
        vals0[4*i+0] = a.x; vals0[4*i+1] = a.y; vals0[4*i+2] = a.z; vals0[4*i+3] = a.w;
        vals1[4*i+0] = b.x; vals1[4*i+1] = b.y; vals1[4*i+2] = b.z; vals1[4*i+3] = b.w;
        sum0 += a.x + a.y + a.z + a.w;
        sq0  += a.x*a.x + a.y*a.y + a.z*a.z + a.w*a.w;
        sum1 += b.x + b.y + b.z + b.w;
        sq1  += b.x*b.x + b.y*b.y + b.z*b.z + b.w*b.w;
    }
    sum0 += __shfl_xor(sum0, 1); sum0 += __shfl_xor(sum0, 2);
    sq0  += __shfl_xor(sq0, 1);  sq0  += __shfl_xor(sq0, 2);
    sum1 += __shfl_xor(sum1, 1); sum1 += __shfl_xor(sum1, 2);
    sq1  += __shfl_xor(sq1, 1);  sq1  += __shfl_xor(sq1, 2);

    float mu0 = sum0 * (1.f / CZd);
    float mu1 = sum1 * (1.f / CZd);
    float rs0 = rsqrtf(sq0 * (1.f / CZd) - mu0 * mu0 + 1e-5f);
    float rs1 = rsqrtf(sq1 * (1.f / CZd) - mu1 * mu1 + 1e-5f);

#pragma unroll
    for (int i = 0; i < 8; ++i) {
#pragma unroll
        for (int jj = 0; jj < 4; ++jj) {
            int e = 16 * i + 4 * sub + jj;
            float w = swb[e], b = swb[CZd + e];
            vals0[4*i+jj] = (vals0[4*i+jj] - mu0) * rs0 * w + b;
            vals1[4*i+jj] = (vals1[4*i+jj] - mu1) * rs1 * w + b;
        }
    }

#pragma unroll
    for (int h = 0; h < NH; ++h) {
        float p0 = 0.f, p1 = 0.f;
#pragma unroll
        for (int i = 0; i < 8; ++i) {
            float4 w4 = *(const float4*)&sWz[h * CZd + 16 * i + 4 * sub];
            p0 += vals0[4*i+0]*w4.x + vals0[4*i+1]*w4.y + vals0[4*i+2]*w4.z + vals0[4*i+3]*w4.w;
            p1 += vals1[4*i+0]*w4.x + vals1[4*i+1]*w4.y + vals1[4*i+2]*w4.z + vals1[4*i+3]*w4.w;
        }
        p0 += __shfl_xor(p0, 1); p0 += __shfl_xor(p0, 2);
        p1 += __shfl_xor(p1, 1); p1 += __shfl_xor(p1, 2);
        if ((h & 3) == sub) {
            sbias[0][h][wv * 16 + g] = p0;
            sbias[1][h][wv * 16 + g] = p1;
        }
    }
    __syncthreads();

    // coalesced store: thread t -> h = t>>4, 4 consecutive k, both q rows
    {
        int h  = t >> 4;
        int c4 = t & 15;
        float4 v0 = *(const float4*)&sbias[0][h][c4 * 4];
        float4 v1 = *(const float4*)&sbias[1][h][c4 * 4];
        *(float4*)&bias[((size_t)h * N_TOK + q0    ) * N_TOK + k0 + c4 * 4] = v0;
        *(float4*)&bias[((size_t)h * N_TOK + q0 + 1) * N_TOK + k0 + c4 * 4] = v1;
    }
}

// ---------------------------------------------------------------------------
// Kernel 2: fused projections, C = s @ W^T (unchanged from round 8)
// grid: (32, 12), block 256
// ---------------------------------------------------------------------------
#define BKP 32

__global__ __launch_bounds__(256) void qkvg_kernel(
    const float* __restrict__ s,
    const float* __restrict__ Wq, const float* __restrict__ bq,
    const float* __restrict__ Wk, const float* __restrict__ Wv,
    const float* __restrict__ Wg, float* __restrict__ qkvg)
{
    __shared__ __align__(16) float As[BKP][68];   // [k][m]
    __shared__ __align__(16) float Bs[BKP][68];   // [k][n]
    int t  = threadIdx.x;
    int m0 = blockIdx.y * 64;
    int n0 = blockIdx.x * 64;
    int sel  = n0 >> 9;
    int nloc = n0 & 511;
    const float* W = (sel == 0) ? Wq : (sel == 1) ? Wk : (sel == 2) ? Wv : Wg;

    int tm = t >> 4, tn = t & 15;
    float acc[4][4] = {};

    for (int kt = 0; kt < 512; kt += BKP) {
#pragma unroll
        for (int i = 0; i < 2; ++i) {
            int idx = t + i * 256;          // 0..511
            int row = idx >> 3;             // 0..63
            int c4  = idx & 7;              // 0..7 -> k-chunk
            float4 a4 = *(const float4*)&s[(size_t)(m0 + row) * 512 + kt + c4 * 4];
            float4 b4 = *(const float4*)&W[(size_t)(nloc + row) * 512 + kt + c4 * 4];
            As[c4*4+0][row] = a4.x; As[c4*4+1][row] = a4.y;
            As[c4*4+2][row] = a4.z; As[c4*4+3][row] = a4.w;
            Bs[c4*4+0][row] = b4.x; Bs[c4*4+1][row] = b4.y;
            Bs[c4*4+2][row] = b4.z; Bs[c4*4+3][row] = b4.w;
        }
        __syncthreads();
#pragma unroll
        for (int kk = 0; kk < BKP; ++kk) {
            float4 a4 = *(const float4*)&As[kk][tm * 4];
            float4 b4 = *(const float4*)&Bs[kk][tn * 4];
            acc[0][0] += a4.x * b4.x; acc[0][1] += a4.x * b4.y;
            acc[0][2] += a4.x * b4.z; acc[0][3] += a4.x * b4.w;
            acc[1][0] += a4.y * b4.x; acc[1][1] += a4.y * b4.y;
            acc[1][2] += a4.y * b4.z; acc[1][3] += a4.y * b4.w;
            acc[2][0] += a4.z * b4.x; acc[2][1] += a4.z * b4.y;
            acc[2][2] += a4.z * b4.z; acc[2][3] += a4.z * b4.w;
            acc[3][0] += a4.w * b4.x; acc[3][1] += a4.w * b4.y;
            acc[3][2] += a4.w * b4.z; acc[3][3] += a4.w * b4.w;
        }
        __syncthreads();
    }

#pragma unroll
    for (int i = 0; i < 4; ++i) {
        int row = m0 + tm * 4 + i;
        float4 v;
        int colb = n0 + tn * 4;
        v.x = acc[i][0]; v.y = acc[i][1]; v.z = acc[i][2]; v.w = acc[i][3];
        if (sel == 0) {
            v.x += bq[colb + 0]; v.y += bq[colb + 1];
            v.z += bq[colb + 2]; v.w += bq[colb + 3];
        }
        *(float4*)&qkvg[(size_t)row * 2048 + colb] = v;
    }
}

// ---------------------------------------------------------------------------
// Kernel 3: flash-style tiled attention.
// v2: logits + online softmax fused in one phase. Each 16-lane group owns one
// q-row and computes ALL 64 k-values of the tile -> row max/sum reduce done
// in-register (shfl_xor 1/2/4/8), no pt round-trip; 3 barriers/tile (was 4).
// grid: (48, 16), block 256
// ---------------------------------------------------------------------------
#define QT 16
#define KT 64

__global__ __launch_bounds__(256) void attn_kernel(
    const float* __restrict__ qkvg, const float* __restrict__ bias,
    float* __restrict__ o_g)
{
    __shared__ float kt_s[KT][32];   // chunk c4 stored at (c4 ^ (row&7))
    __shared__ float vt_s[KT][32];   // row-major plain
    __shared__ __align__(16) float pt[QT][68];
    __shared__ float mrun[QT], lrun[QT], scalef[QT];

    int t  = threadIdx.x;
    int h  = blockIdx.y;
    int Q0 = blockIdx.x * QT;

    int qi_l = t >> 4;     // q-row owned for logits (16 threads per row)
    int c16  = t & 15;
    int d   = t & 31;      // PV: output dim
    int qg  = t >> 5;
    int qi0 = qg * 2, qi1 = qg * 2 + 1;

    float4 qreg[8];
    {
        const float* qrow = qkvg + (size_t)(Q0 + qi_l) * 2048 + h * 32;
#pragma unroll
        for (int j = 0; j < 8; ++j) qreg[j] = ((const float4*)qrow)[j];
    }

    float acc0 = 0.f, acc1 = 0.f;
    if (t < QT) { mrun[t] = -1e30f; lrun[t] = 0.f; }
    __syncthreads();

    const float scale = 0.17677669529663687f; // 1/sqrt(32)

    for (int k0 = 0; k0 < N_TOK; k0 += KT) {
        // ---- stage K/V tile (coalesced: 8 threads = one 128B row line) ----
#pragma unroll
        for (int i = 0; i < 2; ++i) {
            int idx = t + i * 256;
            int row = idx >> 3;
            int c4  = idx & 7;
            const float* kp = qkvg + (size_t)(k0 + row) * 2048 +  512 + h * 32 + c4 * 4;
            const float* vp = qkvg + (size_t)(k0 + row) * 2048 + 1024 + h * 32 + c4 * 4;
            float4 k4 = *(const float4*)kp;
            float4 v4 = *(const float4*)vp;
            int sc4 = c4 ^ (row & 7);
            *(float4*)&kt_s[row][sc4 * 4] = k4;
            *(float4*)&vt_s[row][c4 * 4]  = v4;
        }
        __syncthreads();

        // ---- logits + in-register online softmax (16-lane groups) ----
        {
            float dots[4];
#pragma unroll
            for (int j = 0; j < 4; ++j) {
                int kk = c16 + 16 * j;
                float dot = 0.f;
#pragma unroll
                for (int c4 = 0; c4 < 8; ++c4) {
                    int sc4 = c4 ^ (kk & 7);
                    float4 k4 = *(const float4*)&kt_s[kk][sc4 * 4];
                    float4 q4 = qreg[c4];
                    dot += k4.x*q4.x + k4.y*q4.y + k4.z*q4.z + k4.w*q4.w;
                }
                float b = bias[((size_t)h * N_TOK + (Q0 + qi_l)) * N_TOK + k0 + kk];
                dots[j] = dot * scale + b;
            }
            float mx = fmaxf(fmaxf(dots[0], dots[1]), fmaxf(dots[2], dots[3]));
            mx = fmaxf(mx, __shfl_xor(mx, 1));
            mx = fmaxf(mx, __shfl_xor(mx, 2));
            mx = fmaxf(mx, __shfl_xor(mx, 4));
            mx = fmaxf(mx, __shfl_xor(mx, 8));
            float mold = mrun[qi_l];
            float mnew = fmaxf(mold, mx);
            float ssum = 0.f;
#pragma unroll
            for (int j = 0; j < 4; ++j) {
                float p = __expf(dots[j] - mnew);
                pt[qi_l][c16 + 16 * j] = p;
                ssum += p;
            }
            ssum += __shfl_xor(ssum, 1);
            ssum += __shfl_xor(ssum, 2);
            ssum += __shfl_xor(ssum, 4);
            ssum += __shfl_xor(ssum, 8);
            if (c16 == 0) {
                float sc = __expf(mold - mnew);
                scalef[qi_l] = sc;
                mrun[qi_l]   = mnew;
                lrun[qi_l]   = lrun[qi_l] * sc + ssum;
            }
        }
        __syncthreads();

        // ---- PV accumulate ----
        {
            float s0 = scalef[qi0], s1 = scalef[qi1];
            acc0 *= s0; acc1 *= s1;
#pragma unroll
            for (int kk4 = 0; kk4 < KT; kk4 += 4) {
                float4 p0 = *(const float4*)&pt[qi0][kk4];
                float4 p1 = *(const float4*)&pt[qi1][kk4];
                float v0 = vt_s[kk4+0][d];
                float v1 = vt_s[kk4+1][d];
                float v2 = vt_s[kk4+2][d];
                float v3 = vt_s[kk4+3][d];
                acc0 += p0.x*v0 + p0.y*v1 + p0.z*v2 + p0.w*v3;
                acc1 += p1.x*v0 + p1.y*v1 + p1.z*v2 + p1.w*v3;
            }
        }
        __syncthreads();   // protect kt/vt/pt before next stage
    }

    // ---- epilogue: normalize, sigmoid gate, store ----
    {
        float g0 = qkvg[(size_t)(Q0 + qi0) * 2048 + 1536 + h * 32 + d];
        float g1 = qkvg[(size_t)(Q0 + qi1) * 2048 + 1536 + h * 32 + d];
        float o0 = acc0 / lrun[qi0] / (1.f + __expf(-g0));
        float o1 = acc1 / lrun[qi1] / (1.f + __expf(-g1));
        o_g[(size_t)(Q0 + qi0) * 512 + h * 32 + d] = o0;
        o_g[(size_t)(Q0 + qi1) * 512 + h * 32 + d] = o1;
    }
}

// ---------------------------------------------------------------------------
// Kernel 4: out = o_g @ Wo^T (unchanged from round 8)
// grid: (8, 12), block 256
// ---------------------------------------------------------------------------
__global__ __launch_bounds__(256) void outproj_kernel(
    const float* __restrict__ o_g, const float* __restrict__ Wo,
    float* __restrict__ out)
{
    __shared__ __align__(16) float As[BKP][68];
    __shared__ __align__(16) float Bs[BKP][68];
    int t  = threadIdx.x;
    int m0 = blockIdx.y * 64;
    int n0 = blockIdx.x * 64;

    int tm = t >> 4, tn = t & 15;
    float acc[4][4] = {};

    for (int kt = 0; kt < 512; kt += BKP) {
#pragma unroll
        for (int i = 0; i < 2; ++i) {
            int idx = t + i * 256;
            int row = idx >> 3;
            int c4  = idx & 7;
            float4 a4 = *(const float4*)&o_g[(size_t)(m0 + row) * 512 + kt + c4 * 4];
            float4 b4 = *(const float4*)&Wo[(size_t)(n0 + row) * 512 + kt + c4 * 4];
            As[c4*4+0][row] = a4.x; As[c4*4+1][row] = a4.y;
            As[c4*4+2][row] = a4.z; As[c4*4+3][row] = a4.w;
            Bs[c4*4+0][row] = b4.x; Bs[c4*4+1][row] = b4.y;
            Bs[c4*4+2][row] = b4.z; Bs[c4*4+3][row] = b4.w;
        }
        __syncthreads();
#pragma unroll
        for (int kk = 0; kk < BKP; ++kk) {
            float4 a4 = *(const float4*)&As[kk][tm * 4];
            float4 b4 = *(const float4*)&Bs[kk][tn * 4];
            acc[0][0] += a4.x * b4.x; acc[0][1] += a4.x * b4.y;
            acc[0][2] += a4.x * b4.z; acc[0][3] += a4.x * b4.w;
            acc[1][0] += a4.y * b4.x; acc[1][1] += a4.y * b4.y;
            acc[1][2] += a4.y * b4.z; acc[1][3] += a4.y * b4.w;
            acc[2][0] += a4.z * b4.x; acc[2][1] += a4.z * b4.y;
            acc[2][2] += a4.z * b4.z; acc[2][3] += a4.z * b4.w;
            acc[3][0] += a4.w * b4.x; acc[3][1] += a4.w * b4.y;
            acc[3][2] += a4.w * b4.z; acc[3][3] += a4.w * b4.w;
        }
        __syncthreads();
    }

#pragma unroll
    for (int i = 0; i < 4; ++i) {
        int row = m0 + tm * 4 + i;
        float4 v;
        v.x = acc[i][0]; v.y = acc[i][1]; v.z = acc[i][2]; v.w = acc[i][3];
        *(float4*)&out[(size_t)row * 512 + n0 + tn * 4] = v;
    }
}

// ---------------------------------------------------------------------------
extern "C" void kernel_launch(void* const* d_in, const int* in_sizes, int n_in,
                              void* d_out, int out_size, void* d_ws, size_t ws_size,
                              hipStream_t stream)
{
    const float* s    = (const float*)d_in[0];
    const float* z    = (const float*)d_in[1];
    const float* Wq   = (const float*)d_in[2];
    const float* bq   = (const float*)d_in[3];
    const float* Wk   = (const float*)d_in[4];
    const float* Wv   = (const float*)d_in[5];
    const float* Wg   = (const float*)d_in[6];
    const float* Wo   = (const float*)d_in[7];
    const float* ln_w = (const float*)d_in[8];
    const float* ln_b = (const float*)d_in[9];
    const float* Wz   = (const float*)d_in[10];

    float* ws    = (float*)d_ws;
    float* qkvg  = ws;                                   // 768*2048 floats
    float* biasb = qkvg + (size_t)N_TOK * 2048;          // 16*768*768 floats
    float* o_g   = biasb + (size_t)NH * N_TOK * N_TOK;   // 768*512 floats
    float* out   = (float*)d_out;

    hipLaunchKernelGGL(qkvg_kernel, dim3(32, 12), dim3(256), 0, stream,
                       s, Wq, bq, Wk, Wv, Wg, qkvg);
    hipLaunchKernelGGL(bias_kernel, dim3(12, 384), dim3(256), 0, stream,
                       z, ln_w, ln_b, Wz, biasb);
    hipLaunchKernelGGL(attn_kernel, dim3(48, 16), dim3(256), 0, stream,
                       qkvg, biasb, o_g);
    hipLaunchKernelGGL(outproj_kernel, dim3(8, 12), dim3(256), 0, stream,
                       o_g, Wo, out);
}

// Round 12
// 530.505 us; speedup vs baseline: 2.0908x; 1.0413x over previous
//
#include <hip/hip_runtime.h>
#include <hip/hip_bf16.h>

#define N_TOK 768
#define D_MODEL 512
#define CZd 128
#define NH 16
#define DHd 32

// ---------------------------------------------------------------------------
// Kernel 1 (FUSED): bias + qkvg in one dispatch, interleaved 12:1 so
// HBM-bound bias blocks and VALU-bound qkvg blocks are co-resident and
// overlap. Math of both parts is bit-identical to round-10 kernels.
// grid: (4992), block 256.  bx%13==0 -> qkvg block (384), else bias (4608).
// ---------------------------------------------------------------------------
#define BKP 32

__global__ __launch_bounds__(256) void fused_bias_qkvg_kernel(
    const float* __restrict__ z, const float* __restrict__ ln_w,
    const float* __restrict__ ln_b, const float* __restrict__ Wz,
    float* __restrict__ bias,
    const float* __restrict__ s,
    const float* __restrict__ Wq, const float* __restrict__ bq,
    const float* __restrict__ Wk, const float* __restrict__ Wv,
    const float* __restrict__ Wg, float* __restrict__ qkvg)
{
    // ---- shared (sum of both branches; 35.1 KB) ----
    __shared__ float sWz[NH * CZd];
    __shared__ float swb[2 * CZd];
    __shared__ __align__(16) float sbias[2][NH][68];
    __shared__ __align__(16) float As[BKP][68];
    __shared__ __align__(16) float Bs[BKP][68];

    int t  = threadIdx.x;
    int bx = blockIdx.x;

    if (bx % 13 == 0) {
        // =============== qkvg part: C = s @ W^T ===============
        int qid = bx / 13;              // 0..383
        int n0 = (qid & 31) * 64;
        int m0 = (qid >> 5) * 64;
        int sel  = n0 >> 9;
        int nloc = n0 & 511;
        const float* W = (sel == 0) ? Wq : (sel == 1) ? Wk : (sel == 2) ? Wv : Wg;

        int tm = t >> 4, tn = t & 15;
        float acc[4][4] = {};

        for (int kt = 0; kt < 512; kt += BKP) {
#pragma unroll
            for (int i = 0; i < 2; ++i) {
                int idx = t + i * 256;
                int row = idx >> 3;
                int c4  = idx & 7;
                float4 a4 = *(const float4*)&s[(size_t)(m0 + row) * 512 + kt + c4 * 4];
                float4 b4 = *(const float4*)&W[(size_t)(nloc + row) * 512 + kt + c4 * 4];
                As[c4*4+0][row] = a4.x; As[c4*4+1][row] = a4.y;
                As[c4*4+2][row] = a4.z; As[c4*4+3][row] = a4.w;
                Bs[c4*4+0][row] = b4.x; Bs[c4*4+1][row] = b4.y;
                Bs[c4*4+2][row] = b4.z; Bs[c4*4+3][row] = b4.w;
            }
            __syncthreads();
#pragma unroll
            for (int kk = 0; kk < BKP; ++kk) {
                float4 a4 = *(const float4*)&As[kk][tm * 4];
                float4 b4 = *(const float4*)&Bs[kk][tn * 4];
                acc[0][0] += a4.x * b4.x; acc[0][1] += a4.x * b4.y;
                acc[0][2] += a4.x * b4.z; acc[0][3] += a4.x * b4.w;
                acc[1][0] += a4.y * b4.x; acc[1][1] += a4.y * b4.y;
                acc[1][2] += a4.y * b4.z; acc[1][3] += a4.y * b4.w;
                acc[2][0] += a4.z * b4.x; acc[2][1] += a4.z * b4.y;
                acc[2][2] += a4.z * b4.z; acc[2][3] += a4.z * b4.w;
                acc[3][0] += a4.w * b4.x; acc[3][1] += a4.w * b4.y;
                acc[3][2] += a4.w * b4.z; acc[3][3] += a4.w * b4.w;
            }
            __syncthreads();
        }

#pragma unroll
        for (int i = 0; i < 4; ++i) {
            int row = m0 + tm * 4 + i;
            float4 v;
            int colb = n0 + tn * 4;
            v.x = acc[i][0]; v.y = acc[i][1]; v.z = acc[i][2]; v.w = acc[i][3];
            if (sel == 0) {
                v.x += bq[colb + 0]; v.y += bq[colb + 1];
                v.z += bq[colb + 2]; v.w += bq[colb + 3];
            }
            *(float4*)&qkvg[(size_t)row * 2048 + colb] = v;
        }
    } else {
        // =============== bias part: LayerNorm(z) @ Wz^T ===============
        int bid = bx - bx / 13 - 1;     // 0..4607
        for (int i = t; i < NH * CZd; i += 256) sWz[i] = Wz[i];
        if (t < CZd) { swb[t] = ln_w[t]; swb[CZd + t] = ln_b[t]; }
        __syncthreads();

        int q0  = (bid / 12) * 2;
        int k0  = (bid % 12) * 64;
        int lane = t & 63;
        int wv   = t >> 6;
        int g    = lane >> 2;
        int sub  = lane & 3;
        int k    = k0 + wv * 16 + g;

        const float* zrow0 = z + ((size_t)q0 * N_TOK + k) * CZd;
        const float* zrow1 = zrow0 + (size_t)N_TOK * CZd;

        float vals0[32], vals1[32];
        float sum0 = 0.f, sq0 = 0.f, sum1 = 0.f, sq1 = 0.f;
#pragma unroll
        for (int i = 0; i < 8; ++i) {
            float4 a = *(const float4*)(zrow0 + (sub + 4 * i) * 4);
            float4 b = *(const float4*)(zrow1 + (sub + 4 * i) * 4);
            vals0[4*i+0] = a.x; vals0[4*i+1] = a.y; vals0[4*i+2] = a.z; vals0[4*i+3] = a.w;
            vals1[4*i+0] = b.x; vals1[4*i+1] = b.y; vals1[4*i+2] = b.z; vals1[4*i+3] = b.w;
            sum0 += a.x + a.y + a.z + a.w;
            sq0  += a.x*a.x + a.y*a.y + a.z*a.z + a.w*a.w;
            sum1 += b.x + b.y + b.z + b.w;
            sq1  += b.x*b.x + b.y*b.y + b.z*b.z + b.w*b.w;
        }
        sum0 += __shfl_xor(sum0, 1); sum0 += __shfl_xor(sum0, 2);
        sq0  += __shfl_xor(sq0, 1);  sq0  += __shfl_xor(sq0, 2);
        sum1 += __shfl_xor(sum1, 1); sum1 += __shfl_xor(sum1, 2);
        sq1  += __shfl_xor(sq1, 1);  sq1  += __shfl_xor(sq1, 2);

        float mu0 = sum0 * (1.f / CZd);
        float mu1 = sum1 * (1.f / CZd);
        float rs0 = rsqrtf(sq0 * (1.f / CZd) - mu0 * mu0 + 1e-5f);
        float rs1 = rsqrtf(sq1 * (1.f / CZd) - mu1 * mu1 + 1e-5f);

#pragma unroll
        for (int i = 0; i < 8; ++i) {
#pragma unroll
            for (int jj = 0; jj < 4; ++jj) {
                int e = 16 * i + 4 * sub + jj;
                float w = swb[e], b = swb[CZd + e];
                vals0[4*i+jj] = (vals0[4*i+jj] - mu0) * rs0 * w + b;
                vals1[4*i+jj] = (vals1[4*i+jj] - mu1) * rs1 * w + b;
            }
        }

#pragma unroll
        for (int h = 0; h < NH; ++h) {
            float p0 = 0.f, p1 = 0.f;
#pragma unroll
            for (int i = 0; i < 8; ++i) {
                float4 w4 = *(const float4*)&sWz[h * CZd + 16 * i + 4 * sub];
                p0 += vals0[4*i+0]*w4.x + vals0[4*i+1]*w4.y + vals0[4*i+2]*w4.z + vals0[4*i+3]*w4.w;
                p1 += vals1[4*i+0]*w4.x + vals1[4*i+1]*w4.y + vals1[4*i+2]*w4.z + vals1[4*i+3]*w4.w;
            }
            p0 += __shfl_xor(p0, 1); p0 += __shfl_xor(p0, 2);
            p1 += __shfl_xor(p1, 1); p1 += __shfl_xor(p1, 2);
            if ((h & 3) == sub) {
                sbias[0][h][wv * 16 + g] = p0;
                sbias[1][h][wv * 16 + g] = p1;
            }
        }
        __syncthreads();

        {
            int h  = t >> 4;
            int c4 = t & 15;
            float4 v0 = *(const float4*)&sbias[0][h][c4 * 4];
            float4 v1 = *(const float4*)&sbias[1][h][c4 * 4];
            *(float4*)&bias[((size_t)h * N_TOK + q0    ) * N_TOK + k0 + c4 * 4] = v0;
            *(float4*)&bias[((size_t)h * N_TOK + q0 + 1) * N_TOK + k0 + c4 * 4] = v1;
        }
    }
}

// ---------------------------------------------------------------------------
// Kernel 3: flash-style tiled attention, v3: KT 64 -> 128.
// Halves tile count (12 -> 6) => barriers 36 -> 18, half the softmax/rescale
// passes. Per-k LDS/FMA cost unchanged. grid: (48, 16), block 256.
// ---------------------------------------------------------------------------
#define QT 16
#define KT 128

__global__ __launch_bounds__(256) void attn_kernel(
    const float* __restrict__ qkvg, const float* __restrict__ bias,
    float* __restrict__ o_g)
{
    __shared__ float kt_s[KT][32];   // chunk c4 stored at (c4 ^ (row&7))
    __shared__ float vt_s[KT][32];   // row-major plain
    __shared__ __align__(16) float pt[QT][132];   // 528B rows, 16B-aligned
    __shared__ float mrun[QT], lrun[QT], scalef[QT];

    int t  = threadIdx.x;
    int h  = blockIdx.y;
    int Q0 = blockIdx.x * QT;

    int qi_l = t >> 4;     // q-row owned for logits (16 threads per row)
    int c16  = t & 15;
    int d   = t & 31;      // PV: output dim
    int qg  = t >> 5;
    int qi0 = qg * 2, qi1 = qg * 2 + 1;

    float4 qreg[8];
    {
        const float* qrow = qkvg + (size_t)(Q0 + qi_l) * 2048 + h * 32;
#pragma unroll
        for (int j = 0; j < 8; ++j) qreg[j] = ((const float4*)qrow)[j];
    }

    float acc0 = 0.f, acc1 = 0.f;
    if (t < QT) { mrun[t] = -1e30f; lrun[t] = 0.f; }
    __syncthreads();

    const float scale = 0.17677669529663687f; // 1/sqrt(32)

    for (int k0 = 0; k0 < N_TOK; k0 += KT) {
        // ---- stage K/V tile (coalesced: 8 threads = one 128B row line) ----
#pragma unroll
        for (int i = 0; i < 4; ++i) {
            int idx = t + i * 256;          // 0..1023
            int row = idx >> 3;             // 0..127
            int c4  = idx & 7;
            const float* kp = qkvg + (size_t)(k0 + row) * 2048 +  512 + h * 32 + c4 * 4;
            const float* vp = qkvg + (size_t)(k0 + row) * 2048 + 1024 + h * 32 + c4 * 4;
            float4 k4 = *(const float4*)kp;
            float4 v4 = *(const float4*)vp;
            int sc4 = c4 ^ (row & 7);
            *(float4*)&kt_s[row][sc4 * 4] = k4;
            *(float4*)&vt_s[row][c4 * 4]  = v4;
        }
        __syncthreads();

        // ---- logits + in-register online softmax (16-lane groups) ----
        {
            float dots[8];
#pragma unroll
            for (int j = 0; j < 8; ++j) {
                int kk = c16 + 16 * j;
                float dot = 0.f;
#pragma unroll
                for (int c4 = 0; c4 < 8; ++c4) {
                    int sc4 = c4 ^ (kk & 7);
                    float4 k4 = *(const float4*)&kt_s[kk][sc4 * 4];
                    float4 q4 = qreg[c4];
                    dot += k4.x*q4.x + k4.y*q4.y + k4.z*q4.z + k4.w*q4.w;
                }
                float b = bias[((size_t)h * N_TOK + (Q0 + qi_l)) * N_TOK + k0 + kk];
                dots[j] = dot * scale + b;
            }
            float mx = dots[0];
#pragma unroll
            for (int j = 1; j < 8; ++j) mx = fmaxf(mx, dots[j]);
            mx = fmaxf(mx, __shfl_xor(mx, 1));
            mx = fmaxf(mx, __shfl_xor(mx, 2));
            mx = fmaxf(mx, __shfl_xor(mx, 4));
            mx = fmaxf(mx, __shfl_xor(mx, 8));
            float mold = mrun[qi_l];
            float mnew = fmaxf(mold, mx);
            float ssum = 0.f;
#pragma unroll
            for (int j = 0; j < 8; ++j) {
                float p = __expf(dots[j] - mnew);
                pt[qi_l][c16 + 16 * j] = p;
                ssum += p;
            }
            ssum += __shfl_xor(ssum, 1);
            ssum += __shfl_xor(ssum, 2);
            ssum += __shfl_xor(ssum, 4);
            ssum += __shfl_xor(ssum, 8);
            if (c16 == 0) {
                float sc = __expf(mold - mnew);
                scalef[qi_l] = sc;
                mrun[qi_l]   = mnew;
                lrun[qi_l]   = lrun[qi_l] * sc + ssum;
            }
        }
        __syncthreads();

        // ---- PV accumulate ----
        {
            float s0 = scalef[qi0], s1 = scalef[qi1];
            acc0 *= s0; acc1 *= s1;
#pragma unroll
            for (int kk4 = 0; kk4 < KT; kk4 += 4) {
                float4 p0 = *(const float4*)&pt[qi0][kk4];
                float4 p1 = *(const float4*)&pt[qi1][kk4];
                float v0 = vt_s[kk4+0][d];
                float v1 = vt_s[kk4+1][d];
                float v2 = vt_s[kk4+2][d];
                float v3 = vt_s[kk4+3][d];
                acc0 += p0.x*v0 + p0.y*v1 + p0.z*v2 + p0.w*v3;
                acc1 += p1.x*v0 + p1.y*v1 + p1.z*v2 + p1.w*v3;
            }
        }
        __syncthreads();   // protect kt/vt/pt before next stage
    }

    // ---- epilogue: normalize, sigmoid gate, store ----
    {
        float g0 = qkvg[(size_t)(Q0 + qi0) * 2048 + 1536 + h * 32 + d];
        float g1 = qkvg[(size_t)(Q0 + qi1) * 2048 + 1536 + h * 32 + d];
        float o0 = acc0 / lrun[qi0] / (1.f + __expf(-g0));
        float o1 = acc1 / lrun[qi1] / (1.f + __expf(-g1));
        o_g[(size_t)(Q0 + qi0) * 512 + h * 32 + d] = o0;
        o_g[(size_t)(Q0 + qi1) * 512 + h * 32 + d] = o1;
    }
}

// ---------------------------------------------------------------------------
// Kernel 4: out = o_g @ Wo^T (unchanged)
// grid: (8, 12), block 256
// ---------------------------------------------------------------------------
__global__ __launch_bounds__(256) void outproj_kernel(
    const float* __restrict__ o_g, const float* __restrict__ Wo,
    float* __restrict__ out)
{
    __shared__ __align__(16) float As[BKP][68];
    __shared__ __align__(16) float Bs[BKP][68];
    int t  = threadIdx.x;
    int m0 = blockIdx.y * 64;
    int n0 = blockIdx.x * 64;

    int tm = t >> 4, tn = t & 15;
    float acc[4][4] = {};

    for (int kt = 0; kt < 512; kt += BKP) {
#pragma unroll
        for (int i = 0; i < 2; ++i) {
            int idx = t + i * 256;
            int row = idx >> 3;
            int c4  = idx & 7;
            float4 a4 = *(const float4*)&o_g[(size_t)(m0 + row) * 512 + kt + c4 * 4];
            float4 b4 = *(const float4*)&Wo[(size_t)(n0 + row) * 512 + kt + c4 * 4];
            As[c4*4+0][row] = a4.x; As[c4*4+1][row] = a4.y;
            As[c4*4+2][row] = a4.z; As[c4*4+3][row] = a4.w;
            Bs[c4*4+0][row] = b4.x; Bs[c4*4+1][row] = b4.y;
            Bs[c4*4+2][row] = b4.z; Bs[c4*4+3][row] = b4.w;
        }
        __syncthreads();
#pragma unroll
        for (int kk = 0; kk < BKP; ++kk) {
            float4 a4 = *(const float4*)&As[kk][tm * 4];
            float4 b4 = *(const float4*)&Bs[kk][tn * 4];
            acc[0][0] += a4.x * b4.x; acc[0][1] += a4.x * b4.y;
            acc[0][2] += a4.x * b4.z; acc[0][3] += a4.x * b4.w;
            acc[1][0] += a4.y * b4.x; acc[1][1] += a4.y * b4.y;
            acc[1][2] += a4.y * b4.z; acc[1][3] += a4.y * b4.w;
            acc[2][0] += a4.z * b4.x; acc[2][1] += a4.z * b4.y;
            acc[2][2] += a4.z * b4.z; acc[2][3] += a4.z * b4.w;
            acc[3][0] += a4.w * b4.x; acc[3][1] += a4.w * b4.y;
            acc[3][2] += a4.w * b4.z; acc[3][3] += a4.w * b4.w;
        }
        __syncthreads();
    }

#pragma unroll
    for (int i = 0; i < 4; ++i) {
        int row = m0 + tm * 4 + i;
        float4 v;
        v.x = acc[i][0]; v.y = acc[i][1]; v.z = acc[i][2]; v.w = acc[i][3];
        *(float4*)&out[(size_t)row * 512 + n0 + tn * 4] = v;
    }
}

// ---------------------------------------------------------------------------
extern "C" void kernel_launch(void* const* d_in, const int* in_sizes, int n_in,
                              void* d_out, int out_size, void* d_ws, size_t ws_size,
                              hipStream_t stream)
{
    const float* s    = (const float*)d_in[0];
    const float* z    = (const float*)d_in[1];
    const float* Wq   = (const float*)d_in[2];
    const float* bq   = (const float*)d_in[3];
    const float* Wk   = (const float*)d_in[4];
    const float* Wv   = (const float*)d_in[5];
    const float* Wg   = (const float*)d_in[6];
    const float* Wo   = (const float*)d_in[7];
    const float* ln_w = (const float*)d_in[8];
    const float* ln_b = (const float*)d_in[9];
    const float* Wz   = (const float*)d_in[10];

    float* ws    = (float*)d_ws;
    float* qkvg  = ws;                                   // 768*2048 floats
    float* biasb = qkvg + (size_t)N_TOK * 2048;          // 16*768*768 floats
    float* o_g   = biasb + (size_t)NH * N_TOK * N_TOK;   // 768*512 floats
    float* out   = (float*)d_out;

    hipLaunchKernelGGL(fused_bias_qkvg_kernel, dim3(4992), dim3(256), 0, stream,
                       z, ln_w, ln_b, Wz, biasb,
                       s, Wq, bq, Wk, Wv, Wg, qkvg);
    hipLaunchKernelGGL(attn_kernel, dim3(48, 16), dim3(256), 0, stream,
                       qkvg, biasb, o_g);
    hipLaunchKernelGGL(outproj_kernel, dim3(8, 12), dim3(256), 0, stream,
                       o_g, Wo, out);
}